// Round 6
// baseline (439.391 us; speedup 1.0000x reference)
//
#include <hip/hip_runtime.h>

#define B_DIM   256
#define T_STEPS 2000
#define F_DIM   128
#define TILE    256
#define NT      8     // 7 tiles of 256 + tail of 208

// R4 kernel, unchanged (best so far: 363.7 us total). This round launches it
// TWICE for timing decomposition: dur = overhead + 2*k. Kernel is idempotent
// (pure function of d_in -> d_out), so correctness is unaffected.
__global__ __launch_bounds__(1024) void lif_fused2(
    const float* __restrict__ x, const float* __restrict__ W,
    const float* __restrict__ bias, float* __restrict__ out, int B) {
  const float BETA = 0.8807970779778823f;  // sigmoid(2.0)

  __shared__ __align__(16) float buf[2][TILE];

  const int tid  = threadIdx.x;
  const int lane = tid & 63;
  const int wave = tid >> 6;    // 0..15
  const int sub  = lane & 15;   // float4 index within a row half
  const int grp  = lane >> 4;   // row within this wave's 4-row group
  const int b    = blockIdx.x;

  const float4 wlo = ((const float4*)W)[sub];
  const float4 whi = ((const float4*)W)[sub + 16];
  const float  bs  = bias[0];
  const float* xb  = x + (size_t)b * T_STEPS * F_DIM;
  float* outb = out + (size_t)b * T_STEPS;

  float4 xl[4], xh[4];
  float  v = 0.0f;

  auto tileLen = [&](int c) {
    const int t0 = c * TILE;
    return (T_STEPS - t0 < TILE) ? (T_STEPS - t0) : TILE;
  };

  auto loadRegs = [&](int c) {   // wave w owns tile rows [w*16, w*16+16)
    const int t0 = c * TILE, len = tileLen(c);
#pragma unroll
    for (int q = 0; q < 4; ++q) {
      const int tl = wave * 16 + q * 4;      // wave-uniform guard
      if (tl < len) {
        const float4* row = (const float4*)(xb + (size_t)(t0 + tl + grp) * F_DIM);
        xl[q] = row[sub];
        xh[q] = row[sub + 16];
      }
    }
  };

  auto reduceTo = [&](float* dst, int c) {
    const int len = tileLen(c);
#pragma unroll
    for (int q = 0; q < 4; ++q) {
      const int tl = wave * 16 + q * 4;
      if (tl < len) {
        // --- bit-exact reduction order (absmax 0.0 x5 rounds) — do not reorder
        float pl = xl[q].x * wlo.x;
        pl = fmaf(xl[q].y, wlo.y, pl);
        pl = fmaf(xl[q].z, wlo.z, pl);
        pl = fmaf(xl[q].w, wlo.w, pl);
        float ph = xh[q].x * whi.x;
        ph = fmaf(xh[q].y, whi.y, ph);
        ph = fmaf(xh[q].z, whi.z, ph);
        ph = fmaf(xh[q].w, whi.w, ph);
        float s = pl + ph;                 // == p + shfl_xor(p,16)
        s += __shfl_xor(s, 8, 64);
        s += __shfl_xor(s, 4, 64);
        s += __shfl_xor(s, 2, 64);
        s += __shfl_xor(s, 1, 64);
        if (sub == 0) dst[tl + grp] = s + bs;
      }
    }
  };

  loadRegs(0);
  reduceTo(buf[0], 0);
  __syncthreads();

  for (int c = 0; c < NT; ++c) {
    if (c + 1 < NT) loadRegs(c + 1);   // loads in flight during scan/reduce

    if (wave == 0) {
      const float* cb  = buf[c & 1];
      const int    t0  = c * TILE;
      const int    len = tileLen(c);   // 256 or 208
      const int    ng  = len >> 3;     // groups of 8 steps (32 or 26, even)
      float sreg = 0.0f;

      auto step = [&](float cvv, int tloc) {
        const float vp   = __fadd_rn(__fmul_rn(BETA, v), cvv);
        const bool  fire = (vp >= 1.0f);           // == (vp - VTH >= 0)
        v = fire ? __fsub_rn(vp, 1.0f) : vp;       // subtraction reset
        const float s = fire ? 1.0f : 0.0f;
        if ((tloc & 63) == lane) sreg = s;         // lane owns t&63
      };

      float4 A0 = *(const float4*)&cb[0];
      float4 A1 = *(const float4*)&cb[4];
      for (int gg = 0; gg < ng; gg += 2) {
        float4 Bq0 = *(const float4*)&cb[(gg + 1) * 8];
        float4 Bq1 = *(const float4*)&cb[(gg + 1) * 8 + 4];
        step(A0.x, gg * 8 + 0); step(A0.y, gg * 8 + 1);
        step(A0.z, gg * 8 + 2); step(A0.w, gg * 8 + 3);
        step(A1.x, gg * 8 + 4); step(A1.y, gg * 8 + 5);
        step(A1.z, gg * 8 + 6); step(A1.w, gg * 8 + 7);
        if (gg + 2 < ng) {
          A0 = *(const float4*)&cb[(gg + 2) * 8];
          A1 = *(const float4*)&cb[(gg + 2) * 8 + 4];
        }
        const int tb = (gg + 1) * 8;
        step(Bq0.x, tb + 0); step(Bq0.y, tb + 1);
        step(Bq0.z, tb + 2); step(Bq0.w, tb + 3);
        step(Bq1.x, tb + 4); step(Bq1.y, tb + 5);
        step(Bq1.z, tb + 6); step(Bq1.w, tb + 7);
        if (((gg + 1) & 7) == 7) {                 // end of a 64-step round
          const int tend = tb + 7;                 // tend & 63 == 63
          outb[t0 + (tend - 63) + lane] = sreg;    // coalesced 256B store
        }
      }
      const int rem = len & 63;                    // 0 or 16 (tail tile)
      if (rem && lane < rem)
        outb[t0 + (len & ~63) + lane] = sreg;
    }

    if (c + 1 < NT) reduceTo(buf[(c + 1) & 1], c + 1);
    __syncthreads();
  }

  if (tid == 0) out[(size_t)B_DIM * T_STEPS + b] = v;  // final Vmem
}

extern "C" void kernel_launch(void* const* d_in, const int* in_sizes, int n_in,
                              void* d_out, int out_size, void* d_ws, size_t ws_size,
                              hipStream_t stream) {
  const float* x    = (const float*)d_in[0];
  const float* W    = (const float*)d_in[1];
  const float* bias = (const float*)d_in[2];
  float* out = (float*)d_out;
  const int B = in_sizes[0] / (T_STEPS * F_DIM);  // 256

  // DECOMPOSITION EXPERIMENT: two identical launches (idempotent).
  // dur_new - dur_R4 = per-launch kernel time k4.
  lif_fused2<<<dim3(B), dim3(1024), 0, stream>>>(x, W, bias, out, B);
  lif_fused2<<<dim3(B), dim3(1024), 0, stream>>>(x, W, bias, out, B);
}